// Round 1
// 79.291 us; speedup vs baseline: 1.0371x; 1.0371x over previous
//
#include <hip/hip_runtime.h>
#include <hip/hip_bf16.h>

// (N,C,K,H,W) = (4,3,21,128,128), SCALE=0.5 -> Ho=Wo=64, P=4096
// loss = -(W/N) * sum_{n,p,q} gate_p * exp(-0.5*d2) * (S_p . S_q)
//
// R12: ROI compaction. ROIs are exact {0,1}; roi==0 pixels have S==gS==0
// exactly and contribute exactly 0 to every pair term. ~50% of pixels are
// dead -> ~75% of pair tiles were multiplying zeros. New deterministic
// scan_kernel (per-image prefix scan over the 4096 nearest-resampled roi
// values) assigns compacted slots; prep scatters only active pixels;
// pad slots up to the next 128-multiple are zeroed so tiles stay
// content-agnostic. pairs keeps the static worst-case grid (2112) and
// early-exits tiles beyond the live count (dead blocks write part=0).
// Also: features pre-scaled by sqrt(log2e) (sq terms by log2e) so the
// epilogue is min+exp2+fma (mul removed).
//
// Tile math unchanged from R11 (two MFMA chains per 128x128 tile):
//   c1 = gS_p·S_q + S_p·gS_q     [K=48: A=[gS|S], B=[S|gS], 3 MFMAs]
//   c2 = log2e * (-0.5*d2) EXACT [2 MFMAs, f16 hi/lo + sq hi/lo]
//   w = exp2(min(c2,0)); acc += w*c1  (epilogue: no LDS)

typedef _Float16 v8h __attribute__((ext_vector_type(8)));
typedef float v16f __attribute__((ext_vector_type(16)));

#define NIMG 4
#define KCH 21
#define HIN 128
#define WIN 128
#define PPX 4096
#define TPB 32                 // worst-case 128-tiles per axis
#define TRI 528                // TPB*(TPB+1)/2
#define NBLK (NIMG * TRI)      // 2112

#define WS_S_OFF 0x000000      // 96B/slot [gS(24 f16)|S(24 f16)]  -> ends 0x180000
#define WS_F_OFF 0x180000      // 32B/slot featA                   -> ends 0x200000
#define PART_OFF 0x200000      // 2112 f32                         -> ends 0x202100
#define CNT_OFF  0x202100      // int cnt[4]
#define DEST_OFF 0x202200      // u16 dest[4][4096] = 32KB

// sqrt(log2(e)) folded into the feature scaling; sq accumulates scaled
// squares so c2 comes out of the MFMA already multiplied by log2e.
#define SQRT_LOG2E 1.2011224087864498f

__device__ __forceinline__ float fexp2(float x) {
#if __has_builtin(__builtin_amdgcn_exp2f)
    return __builtin_amdgcn_exp2f(x);
#else
    return __expf(x * 0.69314718055994531f);
#endif
}

// ---- scan: per image, deterministic prefix scan of roi!=0 over the 4096
// nearest-resampled pixels; writes u16 dest slots, cnt[n], and zeroes the
// pad slots [cnt, roundup128(cnt)) so pair tiles read exact zeros. ----
__global__ __launch_bounds__(256) void scan_kernel(
    const float* __restrict__ roi, char* __restrict__ ws)
{
    int n = blockIdx.x, t = threadIdx.x;
    // thread t owns pixels p = t*16 .. t*16+15 (same y; x = x0..x0+15)
    int y  = t >> 2;
    int x0 = (t & 3) * 16;
    const float* row = roi + ((size_t)n * HIN + 2 * y) * WIN + 2 * x0;

    unsigned flags = 0; int cl = 0;
    #pragma unroll
    for (int v = 0; v < 8; v++) {
        float4 q = *(const float4*)(row + 4 * v);   // evens at .x and .z
        if (q.x != 0.f) { flags |= 1u << (2 * v);     cl++; }
        if (q.z != 0.f) { flags |= 1u << (2 * v + 1); cl++; }
    }

    // inclusive wave scan over 64 lanes, then cross-wave via LDS
    int lane = t & 63, wv = t >> 6;
    int v = cl;
    #pragma unroll
    for (int off = 1; off < 64; off <<= 1) {
        int u = __shfl_up(v, off, 64);
        if (lane >= off) v += u;
    }
    __shared__ int wsum[4];
    if (lane == 63) wsum[wv] = v;
    __syncthreads();
    int base = 0;
    #pragma unroll
    for (int k = 0; k < 4; k++) if (k < wv) base += wsum[k];
    int excl  = base + v - cl;
    int total = wsum[0] + wsum[1] + wsum[2] + wsum[3];

    unsigned short* dest = (unsigned short*)(ws + DEST_OFF) + (size_t)n * PPX;
    int p0 = t * 16;
    #pragma unroll
    for (int u = 0; u < 16; u++) {
        if (flags & (1u << u)) dest[p0 + u] = (unsigned short)(excl++);
    }
    if (t == 0) ((int*)(ws + CNT_OFF))[n] = total;

    // zero the pad slots (<=127): S=gS=0 -> c1 contribution 0;
    // featA=0 -> c2 row 0 / bounded<=0 as a column -> w in (0,1], w*0 = 0.
    int padEnd = (total + 127) & ~127;
    if (padEnd > PPX) padEnd = PPX;
    const float4 z4 = make_float4(0.f, 0.f, 0.f, 0.f);
    for (int s = total + t; s < padEnd; s += 256) {
        float4* dS = (float4*)(ws + WS_S_OFF + ((size_t)n * PPX + s) * 96);
        #pragma unroll
        for (int u = 0; u < 6; u++) dS[u] = z4;
        float4* dF = (float4*)(ws + WS_F_OFF + ((size_t)n * PPX + s) * 32);
        dF[0] = z4; dF[1] = z4;
    }
}

// ---- prep: per ACTIVE pixel, one 96B S-record and one 32B F-record,
// scattered to its compacted slot ----
__global__ __launch_bounds__(256) void prep_kernel(
    const float* __restrict__ img, const float* __restrict__ seg,
    const float* __restrict__ roi, const int* __restrict__ lbl,
    char* __restrict__ ws)
{
    int gid = blockIdx.x * 256 + threadIdx.x;     // 16384
    int n = gid >> 12, p = gid & (PPX - 1);
    int y = p >> 6, x = p & 63, iy = 2 * y, ix = 2 * x;
    const float inv_rgb = SQRT_LOG2E / 15.0f, inv_sxy = SQRT_LOG2E / 50.0f;

    float rv = roi[((size_t)n * HIN + iy) * WIN + ix];
    if (rv == 0.0f) return;                       // exact-zero contribution
    int d = ((const unsigned short*)(ws + DEST_OFF))[gid];
    int slot = (n << 12) | d;

    int lb = lbl[((size_t)n * HIN + iy) * WIN + ix];

    float sv[KCH]; float maxs = 0.0f;
    #pragma unroll
    for (int k = 0; k < KCH; k++) {
        const float* sp = seg + ((((size_t)n * KCH + k) * HIN + iy) * WIN + ix);
        float2 a = *(const float2*)sp;
        float2 c = *(const float2*)(sp + WIN);
        float s = 0.25f * (a.x + a.y + c.x + c.y);
        maxs = fmaxf(maxs, s);
        sv[k] = s * rv;
    }
    float gate = (lb == 255) ? 1.0f : fmaxf(rv - maxs, 0.0f);

    union { float4 q[6]; _Float16 e[48]; } rs;
    #pragma unroll
    for (int k = 0; k < KCH; k++) {
        rs.e[k] = (_Float16)(sv[k] * gate);       // gS
        rs.e[24 + k] = (_Float16)sv[k];           // S
    }
    #pragma unroll
    for (int k = KCH; k < 24; k++) { rs.e[k] = (_Float16)0.f; rs.e[24 + k] = (_Float16)0.f; }

    float f[5];
    f[0] = (float)x * inv_sxy;
    f[1] = (float)y * inv_sxy;
    f[2] = img[(((size_t)n * 3 + 0) * HIN + iy) * WIN + ix] * inv_rgb;
    f[3] = img[(((size_t)n * 3 + 1) * HIN + iy) * WIN + ix] * inv_rgb;
    f[4] = img[(((size_t)n * 3 + 2) * HIN + iy) * WIN + ix] * inv_rgb;

    _Float16 hi[5], lo[5];
    float sq = 0.f;
    #pragma unroll
    for (int u = 0; u < 5; u++) {
        hi[u] = (_Float16)f[u];
        lo[u] = (_Float16)(f[u] - (float)hi[u]);
        float fe = (float)hi[u] + (float)lo[u];
        sq = fmaf(fe, fe, sq);                    // scaled: = log2e * ||f||^2
    }
    float sqv = -0.5f * sq;
    _Float16 sqh = (_Float16)sqv;
    _Float16 sql = (_Float16)(sqv - (float)sqh);
    const _Float16 h0 = (_Float16)0.f, h1 = (_Float16)1.f;

    union { float4 q[2]; _Float16 e[16]; } rf;
    #pragma unroll
    for (int u = 0; u < 5; u++) { rf.e[u] = hi[u]; rf.e[8 + u] = lo[u]; }
    rf.e[5] = sqh; rf.e[6] = sql; rf.e[7] = h1;
    rf.e[13] = h0; rf.e[14] = h0; rf.e[15] = h1;

    float4* ds = (float4*)(ws + WS_S_OFF + (size_t)slot * 96);
    #pragma unroll
    for (int u = 0; u < 6; u++) ds[u] = rs.q[u];
    float4* df = (float4*)(ws + WS_F_OFF + (size_t)slot * 32);
    df[0] = rf.q[0]; df[1] = rf.q[1];
}

// ---- pairs: block = upper-tri 128x128 tile over COMPACTED slots; waves
// 2x2 over 64x64; 32x32 subtiles. Tiles beyond the live count early-exit.
// LDS: S 256 rows x 104B stride; F 256 rows x 40B stride
#define LSTR 104
#define FSTR 40
#define SREG_O 0
#define FREG_O 26624
#define RED_O  36864
#define LDS_BYTES 36880

__global__ __launch_bounds__(256)
__attribute__((amdgpu_waves_per_eu(1, 4)))
void pairs_kernel(
    const char* __restrict__ ws, float* __restrict__ part)
{
    __shared__ __align__(16) char smem[LDS_BYTES];
    int b = blockIdx.x;
    int n = b / TRI, r = b - n * TRI;
    int i = 0, rowlen = TPB;
    while (r >= rowlen) { r -= rowlen; rowlen--; i++; }
    int j = i + r;                                 // i <= j
    bool diag = (i == j);

    int cnt = ((const int*)(ws + CNT_OFF))[n];
    int Tn = (cnt + 127) >> 7;                     // live 128-tiles
    if (j >= Tn) {                                 // dead tile (j>=i)
        if (threadIdx.x == 0) part[b] = 0.f;
        return;
    }

    int t = threadIdx.x;
    int lane = t & 63, half = lane >> 5, lr = lane & 31, wv = t >> 6;
    int wq = wv & 1, wp = wv >> 1;

    // ---- stage: i-tile -> rows 0..127, j-tile -> rows 128..255 ----
    {
        const float4* gsi = (const float4*)(ws + WS_S_OFF) + (size_t)(n * PPX + i * 128) * 6;
        #pragma unroll
        for (int k = 0; k < 3; k++) {
            int v = t + k * 256;                   // 0..767
            int row = v / 6, off = v - row * 6;
            float4 vs = gsi[v];
            char* dS = smem + SREG_O + row * LSTR + off * 16;
            *(float2*)dS = make_float2(vs.x, vs.y);
            *(float2*)(dS + 8) = make_float2(vs.z, vs.w);
        }
        const float4* gfi = (const float4*)(ws + WS_F_OFF) + (size_t)(n * PPX + i * 128) * 2;
        {
            int row = t >> 1, off = t & 1;         // 256 threads cover 128 rows x 2
            float4 vf = gfi[t];
            char* dF = smem + FREG_O + row * FSTR + off * 16;
            *(float2*)dF = make_float2(vf.x, vf.y);
            *(float2*)(dF + 8) = make_float2(vf.z, vf.w);
        }
        if (!diag) {
            const float4* gsj = (const float4*)(ws + WS_S_OFF) + (size_t)(n * PPX + j * 128) * 6;
            #pragma unroll
            for (int k = 0; k < 3; k++) {
                int v = t + k * 256;
                int row = v / 6, off = v - row * 6;
                float4 vs = gsj[v];
                char* dS = smem + SREG_O + (128 + row) * LSTR + off * 16;
                *(float2*)dS = make_float2(vs.x, vs.y);
                *(float2*)(dS + 8) = make_float2(vs.z, vs.w);
            }
            const float4* gfj = (const float4*)(ws + WS_F_OFF) + (size_t)(n * PPX + j * 128) * 2;
            int row = t >> 1, off = t & 1;
            float4 vf = gfj[t];
            char* dF = smem + FREG_O + (128 + row) * FSTR + off * 16;
            *(float2*)dF = make_float2(vf.x, vf.y);
            *(float2*)(dF + 8) = make_float2(vf.z, vf.w);
        }
    }
    __syncthreads();

    int jrow0 = diag ? 0 : 128;
    const _Float16 selA = half ? (_Float16)0.f : (_Float16)1.f;
    float ac0 = 0.f, ac1 = 0.f, ac2 = 0.f, ac3 = 0.f;

    #pragma unroll
    for (int sp = 0; sp < 2; sp++) {
        // A-side fragments (p-row), k = half*8 within each K-slice
        int pr = wp * 64 + sp * 32 + lr;
        const char* sb = smem + SREG_O + pr * LSTR;
        const char* fb = smem + FREG_O + pr * FSTR;
        union { v8h h; float2 f[2]; } A0, A1, A2, Af;
        A0.f[0] = *(const float2*)(sb + half * 16);         // gS[0:16]
        A0.f[1] = *(const float2*)(sb + half * 16 + 8);
        A1.f[0] = *(const float2*)(sb + 32 + half * 16);    // gS[16:24]|S[0:8]
        A1.f[1] = *(const float2*)(sb + 32 + half * 16 + 8);
        A2.f[0] = *(const float2*)(sb + 64 + half * 16);    // S[8:24]
        A2.f[1] = *(const float2*)(sb + 64 + half * 16 + 8);
        Af.f[0] = *(const float2*)(fb + half * 16);         // featA half
        Af.f[1] = *(const float2*)(fb + half * 16 + 8);

        #pragma unroll
        for (int s = 0; s < 2; s++) {
            // B-side fragments (q-col)
            int cr = jrow0 + wq * 64 + s * 32 + lr;
            const char* cb = smem + SREG_O + cr * LSTR;
            const char* gb = smem + FREG_O + cr * FSTR;
            union { v8h h; float2 f[2]; } B0, B1, B2;
            union { v8h h; float2 f[2]; _Float16 e[8]; } U, L;
            B0.f[0] = *(const float2*)(cb + 48 + half * 16);        // S[0:16]
            B0.f[1] = *(const float2*)(cb + 48 + half * 16 + 8);
            int o1 = half ? 0 : 80;                                 // S[16:24]|gS[0:8]
            B1.f[0] = *(const float2*)(cb + o1);
            B1.f[1] = *(const float2*)(cb + o1 + 8);
            B2.f[0] = *(const float2*)(cb + 16 + half * 16);        // gS[8:24]
            B2.f[1] = *(const float2*)(cb + 16 + half * 16 + 8);
            U.f[0] = *(const float2*)(gb);      U.f[1] = *(const float2*)(gb + 8);   // [hi5,sqh,sql,1]
            L.f[0] = *(const float2*)(gb + 16); L.f[1] = *(const float2*)(gb + 24);  // [lo5,0,0,1]

            // featB1 = [hi5,1,1,sqh | hi5,0,0,sql], featB2 = [lo5,0,0,0 | lo5,0,0,0]
            union { v8h h; _Float16 e[8]; } Bf1, Bf2;
            Bf1.h = U.h;
            Bf1.e[5] = selA; Bf1.e[6] = selA;
            Bf1.e[7] = half ? U.e[6] : U.e[5];
            Bf2.h = L.h;
            Bf2.e[7] = (_Float16)0.f;

            v16f z = {0.f,0.f,0.f,0.f,0.f,0.f,0.f,0.f,0.f,0.f,0.f,0.f,0.f,0.f,0.f,0.f};
            v16f c2 = __builtin_amdgcn_mfma_f32_32x32x16_f16(Af.h, Bf1.h, z, 0, 0, 0);
            c2 = __builtin_amdgcn_mfma_f32_32x32x16_f16(Af.h, Bf2.h, c2, 0, 0, 0);
            v16f c1 = __builtin_amdgcn_mfma_f32_32x32x16_f16(A0.h, B0.h, z, 0, 0, 0);
            c1 = __builtin_amdgcn_mfma_f32_32x32x16_f16(A1.h, B1.h, c1, 0, 0, 0);
            c1 = __builtin_amdgcn_mfma_f32_32x32x16_f16(A2.h, B2.h, c1, 0, 0, 0);

            #pragma unroll
            for (int rr = 0; rr < 16; rr++) {
                float arg = fminf(c2[rr], 0.0f);   // c2 = log2e * (-0.5*d2)
                float w = fexp2(arg);
                if ((rr & 3) == 0)      ac0 = fmaf(w, c1[rr], ac0);
                else if ((rr & 3) == 1) ac1 = fmaf(w, c1[rr], ac1);
                else if ((rr & 3) == 2) ac2 = fmaf(w, c1[rr], ac2);
                else                    ac3 = fmaf(w, c1[rr], ac3);
            }
        }
    }

    float acc = (ac0 + ac1) + (ac2 + ac3);
    #pragma unroll
    for (int off = 32; off > 0; off >>= 1) acc += __shfl_down(acc, off, 64);
    float* wred = (float*)(smem + RED_O);
    if ((t & 63) == 0) wred[t >> 6] = acc;
    __syncthreads();
    if (t == 0) {
        float partial = (wred[0] + wred[1]) + (wred[2] + wred[3]);
        if (diag) partial *= 0.5f;                 // diag tiles double-count (p,q)/(q,p)
        part[b] = partial;
    }
}

// ---- finalize: deterministic fixed-tree sum of 2112 partials ----
__global__ __launch_bounds__(256) void finalize_kernel(
    const float* __restrict__ part, float* __restrict__ out)
{
    __shared__ float s[256];
    int t = threadIdx.x;
    float v = 0.f;
    #pragma unroll
    for (int k = 0; k < 9; k++) {
        int idx = t + k * 256;
        if (idx < NBLK) v += part[idx];
    }
    s[t] = v;
    __syncthreads();
    #pragma unroll
    for (int off = 128; off > 0; off >>= 1) {
        if (t < off) s[t] += s[t + off];
        __syncthreads();
    }
    if (t == 0) out[0] = s[0] * (-1e-7f / (float)NIMG);
}

extern "C" void kernel_launch(void* const* d_in, const int* in_sizes, int n_in,
                              void* d_out, int out_size, void* d_ws, size_t ws_size,
                              hipStream_t stream) {
    const float* images = (const float*)d_in[0];   // [4,3,128,128]
    const float* seg    = (const float*)d_in[1];   // [4,21,128,128]
    const float* rois   = (const float*)d_in[2];   // [4,128,128]
    const int*   lbl    = (const int*)d_in[3];     // [4,1,128,128]
    float* out = (float*)d_out;
    char*  ws  = (char*)d_ws;
    float* part = (float*)(ws + PART_OFF);

    hipLaunchKernelGGL(scan_kernel, dim3(NIMG), dim3(256), 0, stream,
                       rois, ws);
    hipLaunchKernelGGL(prep_kernel, dim3((NIMG * PPX) / 256), dim3(256), 0, stream,
                       images, seg, rois, lbl, ws);
    hipLaunchKernelGGL(pairs_kernel, dim3(NBLK), dim3(256), 0, stream,
                       (const char*)ws, part);
    hipLaunchKernelGGL(finalize_kernel, dim3(1), dim3(256), 0, stream,
                       (const float*)part, out);
}

// Round 2
// 76.726 us; speedup vs baseline: 1.0718x; 1.0334x over previous
//
#include <hip/hip_runtime.h>
#include <hip/hip_bf16.h>

// (N,C,K,H,W) = (4,3,21,128,128), SCALE=0.5 -> Ho=Wo=64, P=4096
// loss = -(W/N) * sum_{n,p,q} gate_p * exp(-0.5*d2) * (S_p . S_q)
//
// R13: fuse scan into prep (4 kernels -> 3). Each prep block re-derives the
// full per-image roi prefix scan in-block (8 float4 loads/thread, L2-hot)
// instead of a separate scan kernel + u16 dest array round-trip. ROI is
// exactly {0,1}: active pixel => rv==1, so sv = s (no multiply) and
// gate = lb==255 ? 1 : max(1-maxs,0). Pad-slot zeroing handled by the
// bl==15 block of each image; cnt by bl==0. Saves one launch + scan
// kernel + dest traffic; pairs/finalize unchanged from R12.
//
// Tile math (two MFMA chains per 128x128 tile):
//   c1 = gS_p·S_q + S_p·gS_q     [K=48: A=[gS|S], B=[S|gS], 3 MFMAs]
//   c2 = log2e * (-0.5*d2) EXACT [2 MFMAs, f16 hi/lo + sq hi/lo]
//   w = exp2(min(c2,0)); acc += w*c1  (epilogue: no LDS)

typedef _Float16 v8h __attribute__((ext_vector_type(8)));
typedef float v16f __attribute__((ext_vector_type(16)));

#define NIMG 4
#define KCH 21
#define HIN 128
#define WIN 128
#define PPX 4096
#define TPB 32                 // worst-case 128-tiles per axis
#define TRI 528                // TPB*(TPB+1)/2
#define NBLK (NIMG * TRI)      // 2112

#define WS_S_OFF 0x000000      // 96B/slot [gS(24 f16)|S(24 f16)]  -> ends 0x180000
#define WS_F_OFF 0x180000      // 32B/slot featA                   -> ends 0x200000
#define PART_OFF 0x200000      // 2112 f32                         -> ends 0x202100
#define CNT_OFF  0x202100      // int cnt[4]

// sqrt(log2(e)) folded into the feature scaling; sq accumulates scaled
// squares so c2 comes out of the MFMA already multiplied by log2e.
#define SQRT_LOG2E 1.2011224087864498f

__device__ __forceinline__ float fexp2(float x) {
#if __has_builtin(__builtin_amdgcn_exp2f)
    return __builtin_amdgcn_exp2f(x);
#else
    return __expf(x * 0.69314718055994531f);
#endif
}

// ---- prep (fused scan): 16 blocks/image. Every block re-runs the image's
// roi prefix scan (deterministic, L2-hot), then preps its 256 pixels. ----
__global__ __launch_bounds__(256) void prep_kernel(
    const float* __restrict__ img, const float* __restrict__ seg,
    const float* __restrict__ roi, const int* __restrict__ lbl,
    char* __restrict__ ws)
{
    __shared__ int gexcl[256];
    __shared__ unsigned gflags[256];
    __shared__ int wsum[4];

    int n  = blockIdx.x >> 4;
    int bl = blockIdx.x & 15;
    int t  = threadIdx.x;

    // --- full-image scan: thread t owns pixels t*16 .. t*16+15 ---
    {
        int sy = t >> 2, sx0 = (t & 3) * 16;
        const float* srow = roi + ((size_t)n * HIN + 2 * sy) * WIN + 2 * sx0;
        unsigned flags = 0; int cl = 0;
        #pragma unroll
        for (int v = 0; v < 8; v++) {
            float4 q = *(const float4*)(srow + 4 * v);   // evens at .x and .z
            if (q.x != 0.f) { flags |= 1u << (2 * v);     cl++; }
            if (q.z != 0.f) { flags |= 1u << (2 * v + 1); cl++; }
        }
        int lane = t & 63, wv = t >> 6;
        int v = cl;
        #pragma unroll
        for (int off = 1; off < 64; off <<= 1) {
            int u = __shfl_up(v, off, 64);
            if (lane >= off) v += u;
        }
        if (lane == 63) wsum[wv] = v;
        __syncthreads();
        int base = 0;
        #pragma unroll
        for (int k = 0; k < 4; k++) if (k < wv) base += wsum[k];
        gexcl[t] = base + v - cl;
        gflags[t] = flags;
        __syncthreads();
    }
    int total = wsum[0] + wsum[1] + wsum[2] + wsum[3];

    // --- own pixel slot lookup ---
    int p = bl * 256 + t;                         // pixel within image
    int g = p >> 4, o = p & 15;
    unsigned f = gflags[g];
    bool active = (f >> o) & 1u;
    int slot_in = gexcl[g] + __popc(f & ((1u << o) - 1u));

    if (bl == 0 && t == 0) ((int*)(ws + CNT_OFF))[n] = total;

    // --- pad slots [total, roundup128) zeroed by the bl==15 block ---
    if (bl == 15) {
        int padEnd = (total + 127) & ~127;
        if (padEnd > PPX) padEnd = PPX;
        const float4 z4 = make_float4(0.f, 0.f, 0.f, 0.f);
        int s = total + t;
        if (s < padEnd) {                         // <=127 pads, one pass
            float4* dS = (float4*)(ws + WS_S_OFF + ((size_t)n * PPX + s) * 96);
            #pragma unroll
            for (int u = 0; u < 6; u++) dS[u] = z4;
            float4* dF = (float4*)(ws + WS_F_OFF + ((size_t)n * PPX + s) * 32);
            dF[0] = z4; dF[1] = z4;
        }
    }

    if (!active) return;                          // roi==0: exact-zero contribution
    int slot = (n << 12) | slot_in;

    int y = p >> 6, x = p & 63, iy = 2 * y, ix = 2 * x;
    const float inv_rgb = SQRT_LOG2E / 15.0f, inv_sxy = SQRT_LOG2E / 50.0f;

    int lb = lbl[((size_t)n * HIN + iy) * WIN + ix];

    // active => roi == 1 exactly (ROI values are {0,1})
    float sv[KCH]; float maxs = 0.0f;
    #pragma unroll
    for (int k = 0; k < KCH; k++) {
        const float* sp = seg + ((((size_t)n * KCH + k) * HIN + iy) * WIN + ix);
        float2 a = *(const float2*)sp;
        float2 c = *(const float2*)(sp + WIN);
        float s = 0.25f * (a.x + a.y + c.x + c.y);
        maxs = fmaxf(maxs, s);
        sv[k] = s;
    }
    float gate = (lb == 255) ? 1.0f : fmaxf(1.0f - maxs, 0.0f);

    union { float4 q[6]; _Float16 e[48]; } rs;
    #pragma unroll
    for (int k = 0; k < KCH; k++) {
        rs.e[k] = (_Float16)(sv[k] * gate);       // gS
        rs.e[24 + k] = (_Float16)sv[k];           // S
    }
    #pragma unroll
    for (int k = KCH; k < 24; k++) { rs.e[k] = (_Float16)0.f; rs.e[24 + k] = (_Float16)0.f; }

    float fv[5];
    fv[0] = (float)x * inv_sxy;
    fv[1] = (float)y * inv_sxy;
    fv[2] = img[(((size_t)n * 3 + 0) * HIN + iy) * WIN + ix] * inv_rgb;
    fv[3] = img[(((size_t)n * 3 + 1) * HIN + iy) * WIN + ix] * inv_rgb;
    fv[4] = img[(((size_t)n * 3 + 2) * HIN + iy) * WIN + ix] * inv_rgb;

    _Float16 hi[5], lo[5];
    float sq = 0.f;
    #pragma unroll
    for (int u = 0; u < 5; u++) {
        hi[u] = (_Float16)fv[u];
        lo[u] = (_Float16)(fv[u] - (float)hi[u]);
        float fe = (float)hi[u] + (float)lo[u];
        sq = fmaf(fe, fe, sq);                    // scaled: = log2e * ||f||^2
    }
    float sqv = -0.5f * sq;
    _Float16 sqh = (_Float16)sqv;
    _Float16 sql = (_Float16)(sqv - (float)sqh);
    const _Float16 h0 = (_Float16)0.f, h1 = (_Float16)1.f;

    union { float4 q[2]; _Float16 e[16]; } rf;
    #pragma unroll
    for (int u = 0; u < 5; u++) { rf.e[u] = hi[u]; rf.e[8 + u] = lo[u]; }
    rf.e[5] = sqh; rf.e[6] = sql; rf.e[7] = h1;
    rf.e[13] = h0; rf.e[14] = h0; rf.e[15] = h1;

    float4* ds = (float4*)(ws + WS_S_OFF + (size_t)slot * 96);
    #pragma unroll
    for (int u = 0; u < 6; u++) ds[u] = rs.q[u];
    float4* df = (float4*)(ws + WS_F_OFF + (size_t)slot * 32);
    df[0] = rf.q[0]; df[1] = rf.q[1];
}

// ---- pairs: block = upper-tri 128x128 tile over COMPACTED slots; waves
// 2x2 over 64x64; 32x32 subtiles. Tiles beyond the live count early-exit.
// LDS: S 256 rows x 104B stride; F 256 rows x 40B stride
#define LSTR 104
#define FSTR 40
#define SREG_O 0
#define FREG_O 26624
#define RED_O  36864
#define LDS_BYTES 36880

__global__ __launch_bounds__(256)
__attribute__((amdgpu_waves_per_eu(1, 4)))
void pairs_kernel(
    const char* __restrict__ ws, float* __restrict__ part)
{
    __shared__ __align__(16) char smem[LDS_BYTES];
    int b = blockIdx.x;
    int n = b / TRI, r = b - n * TRI;
    int i = 0, rowlen = TPB;
    while (r >= rowlen) { r -= rowlen; rowlen--; i++; }
    int j = i + r;                                 // i <= j
    bool diag = (i == j);

    int cnt = ((const int*)(ws + CNT_OFF))[n];
    int Tn = (cnt + 127) >> 7;                     // live 128-tiles
    if (j >= Tn) {                                 // dead tile (j>=i)
        if (threadIdx.x == 0) part[b] = 0.f;
        return;
    }

    int t = threadIdx.x;
    int lane = t & 63, half = lane >> 5, lr = lane & 31, wv = t >> 6;
    int wq = wv & 1, wp = wv >> 1;

    // ---- stage: i-tile -> rows 0..127, j-tile -> rows 128..255 ----
    {
        const float4* gsi = (const float4*)(ws + WS_S_OFF) + (size_t)(n * PPX + i * 128) * 6;
        #pragma unroll
        for (int k = 0; k < 3; k++) {
            int v = t + k * 256;                   // 0..767
            int row = v / 6, off = v - row * 6;
            float4 vs = gsi[v];
            char* dS = smem + SREG_O + row * LSTR + off * 16;
            *(float2*)dS = make_float2(vs.x, vs.y);
            *(float2*)(dS + 8) = make_float2(vs.z, vs.w);
        }
        const float4* gfi = (const float4*)(ws + WS_F_OFF) + (size_t)(n * PPX + i * 128) * 2;
        {
            int row = t >> 1, off = t & 1;         // 256 threads cover 128 rows x 2
            float4 vf = gfi[t];
            char* dF = smem + FREG_O + row * FSTR + off * 16;
            *(float2*)dF = make_float2(vf.x, vf.y);
            *(float2*)(dF + 8) = make_float2(vf.z, vf.w);
        }
        if (!diag) {
            const float4* gsj = (const float4*)(ws + WS_S_OFF) + (size_t)(n * PPX + j * 128) * 6;
            #pragma unroll
            for (int k = 0; k < 3; k++) {
                int v = t + k * 256;
                int row = v / 6, off = v - row * 6;
                float4 vs = gsj[v];
                char* dS = smem + SREG_O + (128 + row) * LSTR + off * 16;
                *(float2*)dS = make_float2(vs.x, vs.y);
                *(float2*)(dS + 8) = make_float2(vs.z, vs.w);
            }
            const float4* gfj = (const float4*)(ws + WS_F_OFF) + (size_t)(n * PPX + j * 128) * 2;
            int row = t >> 1, off = t & 1;
            float4 vf = gfj[t];
            char* dF = smem + FREG_O + (128 + row) * FSTR + off * 16;
            *(float2*)dF = make_float2(vf.x, vf.y);
            *(float2*)(dF + 8) = make_float2(vf.z, vf.w);
        }
    }
    __syncthreads();

    int jrow0 = diag ? 0 : 128;
    const _Float16 selA = half ? (_Float16)0.f : (_Float16)1.f;
    float ac0 = 0.f, ac1 = 0.f, ac2 = 0.f, ac3 = 0.f;

    #pragma unroll
    for (int sp = 0; sp < 2; sp++) {
        // A-side fragments (p-row), k = half*8 within each K-slice
        int pr = wp * 64 + sp * 32 + lr;
        const char* sb = smem + SREG_O + pr * LSTR;
        const char* fb = smem + FREG_O + pr * FSTR;
        union { v8h h; float2 f[2]; } A0, A1, A2, Af;
        A0.f[0] = *(const float2*)(sb + half * 16);         // gS[0:16]
        A0.f[1] = *(const float2*)(sb + half * 16 + 8);
        A1.f[0] = *(const float2*)(sb + 32 + half * 16);    // gS[16:24]|S[0:8]
        A1.f[1] = *(const float2*)(sb + 32 + half * 16 + 8);
        A2.f[0] = *(const float2*)(sb + 64 + half * 16);    // S[8:24]
        A2.f[1] = *(const float2*)(sb + 64 + half * 16 + 8);
        Af.f[0] = *(const float2*)(fb + half * 16);         // featA half
        Af.f[1] = *(const float2*)(fb + half * 16 + 8);

        #pragma unroll
        for (int s = 0; s < 2; s++) {
            // B-side fragments (q-col)
            int cr = jrow0 + wq * 64 + s * 32 + lr;
            const char* cb = smem + SREG_O + cr * LSTR;
            const char* gb = smem + FREG_O + cr * FSTR;
            union { v8h h; float2 f[2]; } B0, B1, B2;
            union { v8h h; float2 f[2]; _Float16 e[8]; } U, L;
            B0.f[0] = *(const float2*)(cb + 48 + half * 16);        // S[0:16]
            B0.f[1] = *(const float2*)(cb + 48 + half * 16 + 8);
            int o1 = half ? 0 : 80;                                 // S[16:24]|gS[0:8]
            B1.f[0] = *(const float2*)(cb + o1);
            B1.f[1] = *(const float2*)(cb + o1 + 8);
            B2.f[0] = *(const float2*)(cb + 16 + half * 16);        // gS[8:24]
            B2.f[1] = *(const float2*)(cb + 16 + half * 16 + 8);
            U.f[0] = *(const float2*)(gb);      U.f[1] = *(const float2*)(gb + 8);   // [hi5,sqh,sql,1]
            L.f[0] = *(const float2*)(gb + 16); L.f[1] = *(const float2*)(gb + 24);  // [lo5,0,0,1]

            // featB1 = [hi5,1,1,sqh | hi5,0,0,sql], featB2 = [lo5,0,0,0 | lo5,0,0,0]
            union { v8h h; _Float16 e[8]; } Bf1, Bf2;
            Bf1.h = U.h;
            Bf1.e[5] = selA; Bf1.e[6] = selA;
            Bf1.e[7] = half ? U.e[6] : U.e[5];
            Bf2.h = L.h;
            Bf2.e[7] = (_Float16)0.f;

            v16f z = {0.f,0.f,0.f,0.f,0.f,0.f,0.f,0.f,0.f,0.f,0.f,0.f,0.f,0.f,0.f,0.f};
            v16f c2 = __builtin_amdgcn_mfma_f32_32x32x16_f16(Af.h, Bf1.h, z, 0, 0, 0);
            c2 = __builtin_amdgcn_mfma_f32_32x32x16_f16(Af.h, Bf2.h, c2, 0, 0, 0);
            v16f c1 = __builtin_amdgcn_mfma_f32_32x32x16_f16(A0.h, B0.h, z, 0, 0, 0);
            c1 = __builtin_amdgcn_mfma_f32_32x32x16_f16(A1.h, B1.h, c1, 0, 0, 0);
            c1 = __builtin_amdgcn_mfma_f32_32x32x16_f16(A2.h, B2.h, c1, 0, 0, 0);

            #pragma unroll
            for (int rr = 0; rr < 16; rr++) {
                float arg = fminf(c2[rr], 0.0f);   // c2 = log2e * (-0.5*d2)
                float w = fexp2(arg);
                if ((rr & 3) == 0)      ac0 = fmaf(w, c1[rr], ac0);
                else if ((rr & 3) == 1) ac1 = fmaf(w, c1[rr], ac1);
                else if ((rr & 3) == 2) ac2 = fmaf(w, c1[rr], ac2);
                else                    ac3 = fmaf(w, c1[rr], ac3);
            }
        }
    }

    float acc = (ac0 + ac1) + (ac2 + ac3);
    #pragma unroll
    for (int off = 32; off > 0; off >>= 1) acc += __shfl_down(acc, off, 64);
    float* wred = (float*)(smem + RED_O);
    if ((t & 63) == 0) wred[t >> 6] = acc;
    __syncthreads();
    if (t == 0) {
        float partial = (wred[0] + wred[1]) + (wred[2] + wred[3]);
        if (diag) partial *= 0.5f;                 // diag tiles double-count (p,q)/(q,p)
        part[b] = partial;
    }
}

// ---- finalize: deterministic fixed-tree sum of 2112 partials ----
__global__ __launch_bounds__(256) void finalize_kernel(
    const float* __restrict__ part, float* __restrict__ out)
{
    __shared__ float s[256];
    int t = threadIdx.x;
    float v = 0.f;
    #pragma unroll
    for (int k = 0; k < 9; k++) {
        int idx = t + k * 256;
        if (idx < NBLK) v += part[idx];
    }
    s[t] = v;
    __syncthreads();
    #pragma unroll
    for (int off = 128; off > 0; off >>= 1) {
        if (t < off) s[t] += s[t + off];
        __syncthreads();
    }
    if (t == 0) out[0] = s[0] * (-1e-7f / (float)NIMG);
}

extern "C" void kernel_launch(void* const* d_in, const int* in_sizes, int n_in,
                              void* d_out, int out_size, void* d_ws, size_t ws_size,
                              hipStream_t stream) {
    const float* images = (const float*)d_in[0];   // [4,3,128,128]
    const float* seg    = (const float*)d_in[1];   // [4,21,128,128]
    const float* rois   = (const float*)d_in[2];   // [4,128,128]
    const int*   lbl    = (const int*)d_in[3];     // [4,1,128,128]
    float* out = (float*)d_out;
    char*  ws  = (char*)d_ws;
    float* part = (float*)(ws + PART_OFF);

    hipLaunchKernelGGL(prep_kernel, dim3((NIMG * PPX) / 256), dim3(256), 0, stream,
                       images, seg, rois, lbl, ws);
    hipLaunchKernelGGL(pairs_kernel, dim3(NBLK), dim3(256), 0, stream,
                       (const char*)ws, part);
    hipLaunchKernelGGL(finalize_kernel, dim3(1), dim3(256), 0, stream,
                       (const float*)part, out);
}